// Round 3
// baseline (464.467 us; speedup 1.0000x reference)
//
#include <hip/hip_runtime.h>

// LearnedRouter: logits = x[T,H] @ W[E,H]^T ; softmax ; top-2.
// T=16384, H=4096, E=8. Output flat: scores[T*8] | weights[T*2] | idx[T*2] (fp32).
//
// R3: W served from the LDS pipe instead of the vector-memory pipe.
// W (128 KB) is staged per-block in 4 chunks of 32 KB; inner loop reads it
// with ds_read_b128 while the global pipe streams only x (the irreducible
// 256 MB). Block = 512 thr (8 waves x 4 rows = 32 rows), grid = 512.

#define ROUTER_H4 1024       // float4 per row (H=4096)
#define ROUTER_E 8
#define ROWS_PER_WAVE 4
#define CHUNK 256            // float4 per expert per chunk (32 KB chunk)
#define NCHUNK (ROUTER_H4 / CHUNK)

__global__ __launch_bounds__(512, 4) void learned_router_kernel(
    const float* __restrict__ x, const float* __restrict__ W,
    float* __restrict__ out_scores, float* __restrict__ out_w,
    float* __restrict__ out_idx, int n_rows)
{
    __shared__ float4 wlds[ROUTER_E][CHUNK];   // 32 KB

    const int tid  = (int)threadIdx.x;          // 0..511
    const int wv   = tid >> 6;                  // wave in block: 0..7
    const int lane = tid & 63;
    const int row0 = (int)blockIdx.x * (8 * ROWS_PER_WAVE) + wv * ROWS_PER_WAVE;

    const float4* __restrict__ x4 = (const float4*)x;
    const float4* __restrict__ W4 = (const float4*)W;

    float acc[ROWS_PER_WAVE][ROUTER_E];
#pragma unroll
    for (int r = 0; r < ROWS_PER_WAVE; ++r)
#pragma unroll
        for (int e = 0; e < ROUTER_E; ++e) acc[r][e] = 0.f;

    for (int c = 0; c < NCHUNK; ++c) {
        // ---- stage 32 KB chunk: 2048 float4 / 512 threads = 4 each ----
#pragma unroll
        for (int k = 0; k < 4; ++k) {
            const int flat = k * 512 + tid;         // 0..2047, coalesced
            const int e    = flat >> 8;             // /CHUNK
            const int pos  = flat & (CHUNK - 1);
            wlds[e][pos] = W4[e * ROUTER_H4 + c * CHUNK + pos];
        }
        __syncthreads();

        // ---- compute: 4 inner iters of 64 float4 positions ----
#pragma unroll
        for (int inner = 0; inner < CHUNK / 64; ++inner) {
            const int hpos = c * CHUNK + inner * 64 + lane;
            float4 xv[ROWS_PER_WAVE];
#pragma unroll
            for (int r = 0; r < ROWS_PER_WAVE; ++r)
                xv[r] = x4[(size_t)(row0 + r) * ROUTER_H4 + hpos];
#pragma unroll
            for (int e = 0; e < ROUTER_E; ++e) {
                const float4 w4 = wlds[e][inner * 64 + lane];
#pragma unroll
                for (int r = 0; r < ROWS_PER_WAVE; ++r)
                    acc[r][e] += xv[r].x * w4.x + xv[r].y * w4.y
                               + xv[r].z * w4.z + xv[r].w * w4.w;
            }
        }
        __syncthreads();
    }

    // ---- wave butterfly reduction (64 lanes) ----
#pragma unroll
    for (int off = 32; off > 0; off >>= 1) {
#pragma unroll
        for (int r = 0; r < ROWS_PER_WAVE; ++r)
#pragma unroll
            for (int e = 0; e < ROUTER_E; ++e)
                acc[r][e] += __shfl_xor(acc[r][e], off, 64);
    }

    if (lane == 0) {
#pragma unroll
        for (int r = 0; r < ROWS_PER_WAVE; ++r) {
            const int row = row0 + r;
            float m = acc[r][0];
#pragma unroll
            for (int e = 1; e < ROUTER_E; ++e) m = fmaxf(m, acc[r][e]);
            float p[ROUTER_E];
            float s = 0.f;
#pragma unroll
            for (int e = 0; e < ROUTER_E; ++e) { p[e] = __expf(acc[r][e] - m); s += p[e]; }
            const float inv = 1.f / s;
#pragma unroll
            for (int e = 0; e < ROUTER_E; ++e) p[e] *= inv;

            float4* os = (float4*)(out_scores + (size_t)row * ROUTER_E);
            os[0] = make_float4(p[0], p[1], p[2], p[3]);
            os[1] = make_float4(p[4], p[5], p[6], p[7]);

            // top-2, lowest-index tie-break (matches jax.lax.top_k)
            int i0 = 0;
#pragma unroll
            for (int e = 1; e < ROUTER_E; ++e) if (p[e] > p[i0]) i0 = e;
            int i1 = (i0 == 0) ? 1 : 0;
#pragma unroll
            for (int e = 0; e < ROUTER_E; ++e) if (e != i0 && p[e] > p[i1]) i1 = e;

            *(float2*)(out_w + (size_t)row * 2)   = make_float2(p[i0], p[i1]);
            *(float2*)(out_idx + (size_t)row * 2) = make_float2((float)i0, (float)i1);
        }
    }
}

extern "C" void kernel_launch(void* const* d_in, const int* in_sizes, int n_in,
                              void* d_out, int out_size, void* d_ws, size_t ws_size,
                              hipStream_t stream) {
    const float* x = (const float*)d_in[0];
    const float* W = (const float*)d_in[1];
    const int T = in_sizes[0] / (ROUTER_H4 * 4);     // 16384
    (void)n_in; (void)d_ws; (void)ws_size; (void)out_size;

    float* out = (float*)d_out;
    float* out_scores = out;
    float* out_w   = out + (size_t)T * ROUTER_E;
    float* out_idx = out_w + (size_t)T * 2;

    const int rows_per_block = 8 * ROWS_PER_WAVE;    // 32
    const int grid = (T + rows_per_block - 1) / rows_per_block;  // 512
    learned_router_kernel<<<grid, 512, 0, stream>>>(x, W, out_scores, out_w, out_idx, T);
}

// Round 4
// 377.267 us; speedup vs baseline: 1.2311x; 1.2311x over previous
//
#include <hip/hip_runtime.h>

// LearnedRouter: logits = x[T,H] @ W[E,H]^T ; softmax ; top-2.
// T=16384, H=4096, E=8. Output flat: scores[T*8] | weights[T*2] | idx[T*2] (fp32).
//
// R4: same W-in-LDS structure as R3, but WITHOUT the min-waves launch_bounds
// clause. R3's __launch_bounds__(512,4) capped VGPRs at 64 -> acc/xv spilled
// to scratch -> 311 MB of HBM write traffic. Here the allocator gets the
// full 256-VGPR budget (~90 needed), no spill; LDS (32 KB) still allows
// 2+ blocks/CU.

#define ROUTER_H4 1024       // float4 per row (H=4096)
#define ROUTER_E 8
#define ROWS_PER_WAVE 4
#define CHUNK 256            // float4 per expert per chunk (32 KB chunk)
#define NCHUNK (ROUTER_H4 / CHUNK)

__global__ __launch_bounds__(512) void learned_router_kernel(
    const float* __restrict__ x, const float* __restrict__ W,
    float* __restrict__ out_scores, float* __restrict__ out_w,
    float* __restrict__ out_idx, int n_rows)
{
    __shared__ float4 wlds[ROUTER_E][CHUNK];   // 32 KB

    const int tid  = (int)threadIdx.x;          // 0..511
    const int wv   = tid >> 6;                  // wave in block: 0..7
    const int lane = tid & 63;
    const int row0 = (int)blockIdx.x * (8 * ROWS_PER_WAVE) + wv * ROWS_PER_WAVE;

    const float4* __restrict__ x4 = (const float4*)x;
    const float4* __restrict__ W4 = (const float4*)W;

    float acc[ROWS_PER_WAVE][ROUTER_E];
#pragma unroll
    for (int r = 0; r < ROWS_PER_WAVE; ++r)
#pragma unroll
        for (int e = 0; e < ROUTER_E; ++e) acc[r][e] = 0.f;

    for (int c = 0; c < NCHUNK; ++c) {
        // ---- stage 32 KB chunk: 2048 float4 / 512 threads = 4 each ----
#pragma unroll
        for (int k = 0; k < 4; ++k) {
            const int flat = k * 512 + tid;         // 0..2047, coalesced
            const int e    = flat >> 8;             // /CHUNK
            const int pos  = flat & (CHUNK - 1);
            wlds[e][pos] = W4[e * ROUTER_H4 + c * CHUNK + pos];
        }
        __syncthreads();

        // ---- compute: 4 inner iters of 64 float4 positions ----
#pragma unroll
        for (int inner = 0; inner < CHUNK / 64; ++inner) {
            const int hpos = c * CHUNK + inner * 64 + lane;
            float4 xv[ROWS_PER_WAVE];
#pragma unroll
            for (int r = 0; r < ROWS_PER_WAVE; ++r)
                xv[r] = x4[(size_t)(row0 + r) * ROUTER_H4 + hpos];
#pragma unroll
            for (int e = 0; e < ROUTER_E; ++e) {
                const float4 w4 = wlds[e][inner * 64 + lane];
#pragma unroll
                for (int r = 0; r < ROWS_PER_WAVE; ++r)
                    acc[r][e] += xv[r].x * w4.x + xv[r].y * w4.y
                               + xv[r].z * w4.z + xv[r].w * w4.w;
            }
        }
        __syncthreads();
    }

    // ---- wave butterfly reduction (64 lanes) ----
#pragma unroll
    for (int off = 32; off > 0; off >>= 1) {
#pragma unroll
        for (int r = 0; r < ROWS_PER_WAVE; ++r)
#pragma unroll
            for (int e = 0; e < ROUTER_E; ++e)
                acc[r][e] += __shfl_xor(acc[r][e], off, 64);
    }

    if (lane == 0) {
#pragma unroll
        for (int r = 0; r < ROWS_PER_WAVE; ++r) {
            const int row = row0 + r;
            float m = acc[r][0];
#pragma unroll
            for (int e = 1; e < ROUTER_E; ++e) m = fmaxf(m, acc[r][e]);
            float p[ROUTER_E];
            float s = 0.f;
#pragma unroll
            for (int e = 0; e < ROUTER_E; ++e) { p[e] = __expf(acc[r][e] - m); s += p[e]; }
            const float inv = 1.f / s;
#pragma unroll
            for (int e = 0; e < ROUTER_E; ++e) p[e] *= inv;

            float4* os = (float4*)(out_scores + (size_t)row * ROUTER_E);
            os[0] = make_float4(p[0], p[1], p[2], p[3]);
            os[1] = make_float4(p[4], p[5], p[6], p[7]);

            // top-2, lowest-index tie-break (matches jax.lax.top_k)
            int i0 = 0;
#pragma unroll
            for (int e = 1; e < ROUTER_E; ++e) if (p[e] > p[i0]) i0 = e;
            int i1 = (i0 == 0) ? 1 : 0;
#pragma unroll
            for (int e = 0; e < ROUTER_E; ++e) if (e != i0 && p[e] > p[i1]) i1 = e;

            *(float2*)(out_w + (size_t)row * 2)   = make_float2(p[i0], p[i1]);
            *(float2*)(out_idx + (size_t)row * 2) = make_float2((float)i0, (float)i1);
        }
    }
}

extern "C" void kernel_launch(void* const* d_in, const int* in_sizes, int n_in,
                              void* d_out, int out_size, void* d_ws, size_t ws_size,
                              hipStream_t stream) {
    const float* x = (const float*)d_in[0];
    const float* W = (const float*)d_in[1];
    const int T = in_sizes[0] / (ROUTER_H4 * 4);     // 16384
    (void)n_in; (void)d_ws; (void)ws_size; (void)out_size;

    float* out = (float*)d_out;
    float* out_scores = out;
    float* out_w   = out + (size_t)T * ROUTER_E;
    float* out_idx = out_w + (size_t)T * 2;

    const int rows_per_block = 8 * ROWS_PER_WAVE;    // 32
    const int grid = (T + rows_per_block - 1) / rows_per_block;  // 512
    learned_router_kernel<<<grid, 512, 0, stream>>>(x, W, out_scores, out_w, out_idx, T);
}

// Round 5
// 370.751 us; speedup vs baseline: 1.2528x; 1.0176x over previous
//
#include <hip/hip_runtime.h>

// LearnedRouter: logits = x[T,H] @ W[E,H]^T ; softmax ; top-2.
// T=16384, H=4096, E=8. Output flat: scores[T*8] | weights[T*2] | idx[T*2] (fp32).
//
// R5: attack latency-boundedness (R1/R2/R4 delivered 23/11.5/4.2 B/cyc/CU —
// rate tracks resident-wave count, not traffic). Block = 1024 thr (16 waves,
// 1 block/CU, grid=256=CU count); W staged in 2x64KB LDS chunks so the
// K-loop runs 8 barrier-free iterations per phase with ~8KB x in flight
// per wave (128 KB/CU outstanding). No min-waves launch_bounds (R3 spill
// lesson); VGPR target <=128 for 4 waves/SIMD.

#define ROUTER_H4 1024       // float4 per row (H=4096)
#define ROUTER_E 8
#define ROWS_PER_WAVE 4
#define CHUNK 512            // float4 per expert per chunk (64 KB chunk)
#define NCHUNK (ROUTER_H4 / CHUNK)   // 2

__global__ __launch_bounds__(1024) void learned_router_kernel(
    const float* __restrict__ x, const float* __restrict__ W,
    float* __restrict__ out_scores, float* __restrict__ out_w,
    float* __restrict__ out_idx, int n_rows)
{
    __shared__ float4 wlds[ROUTER_E][CHUNK];   // 64 KB

    const int tid  = (int)threadIdx.x;          // 0..1023
    const int wv   = tid >> 6;                  // wave in block: 0..15
    const int lane = tid & 63;
    const int row0 = (int)blockIdx.x * (16 * ROWS_PER_WAVE) + wv * ROWS_PER_WAVE;

    const float4* __restrict__ x4 = (const float4*)x;
    const float4* __restrict__ W4 = (const float4*)W;

    float acc[ROWS_PER_WAVE][ROUTER_E];
#pragma unroll
    for (int r = 0; r < ROWS_PER_WAVE; ++r)
#pragma unroll
        for (int e = 0; e < ROUTER_E; ++e) acc[r][e] = 0.f;

    for (int c = 0; c < NCHUNK; ++c) {
        // ---- stage 64 KB chunk: 4096 float4 / 1024 threads = 4 each ----
#pragma unroll
        for (int k = 0; k < 4; ++k) {
            const int flat = k * 1024 + tid;        // 0..4095, coalesced
            const int e    = flat >> 9;             // /CHUNK
            const int pos  = flat & (CHUNK - 1);
            wlds[e][pos] = W4[e * ROUTER_H4 + c * CHUNK + pos];
        }
        __syncthreads();

        // ---- compute: 8 barrier-free iters of 64 float4 positions ----
#pragma unroll 2
        for (int inner = 0; inner < CHUNK / 64; ++inner) {
            const int idx  = inner * 64 + lane;
            const int hpos = c * CHUNK + idx;
            float4 xv[ROWS_PER_WAVE];
#pragma unroll
            for (int r = 0; r < ROWS_PER_WAVE; ++r)
                xv[r] = x4[(size_t)(row0 + r) * ROUTER_H4 + hpos];
#pragma unroll
            for (int e = 0; e < ROUTER_E; ++e) {
                const float4 w4 = wlds[e][idx];
#pragma unroll
                for (int r = 0; r < ROWS_PER_WAVE; ++r)
                    acc[r][e] += xv[r].x * w4.x + xv[r].y * w4.y
                               + xv[r].z * w4.z + xv[r].w * w4.w;
            }
        }
        __syncthreads();
    }

    // ---- wave butterfly reduction (64 lanes) ----
#pragma unroll
    for (int off = 32; off > 0; off >>= 1) {
#pragma unroll
        for (int r = 0; r < ROWS_PER_WAVE; ++r)
#pragma unroll
            for (int e = 0; e < ROUTER_E; ++e)
                acc[r][e] += __shfl_xor(acc[r][e], off, 64);
    }

    if (lane == 0) {
#pragma unroll
        for (int r = 0; r < ROWS_PER_WAVE; ++r) {
            const int row = row0 + r;
            float m = acc[r][0];
#pragma unroll
            for (int e = 1; e < ROUTER_E; ++e) m = fmaxf(m, acc[r][e]);
            float p[ROUTER_E];
            float s = 0.f;
#pragma unroll
            for (int e = 0; e < ROUTER_E; ++e) { p[e] = __expf(acc[r][e] - m); s += p[e]; }
            const float inv = 1.f / s;
#pragma unroll
            for (int e = 0; e < ROUTER_E; ++e) p[e] *= inv;

            float4* os = (float4*)(out_scores + (size_t)row * ROUTER_E);
            os[0] = make_float4(p[0], p[1], p[2], p[3]);
            os[1] = make_float4(p[4], p[5], p[6], p[7]);

            // top-2, lowest-index tie-break (matches jax.lax.top_k)
            int i0 = 0;
#pragma unroll
            for (int e = 1; e < ROUTER_E; ++e) if (p[e] > p[i0]) i0 = e;
            int i1 = (i0 == 0) ? 1 : 0;
#pragma unroll
            for (int e = 0; e < ROUTER_E; ++e) if (e != i0 && p[e] > p[i1]) i1 = e;

            *(float2*)(out_w + (size_t)row * 2)   = make_float2(p[i0], p[i1]);
            *(float2*)(out_idx + (size_t)row * 2) = make_float2((float)i0, (float)i1);
        }
    }
}

extern "C" void kernel_launch(void* const* d_in, const int* in_sizes, int n_in,
                              void* d_out, int out_size, void* d_ws, size_t ws_size,
                              hipStream_t stream) {
    const float* x = (const float*)d_in[0];
    const float* W = (const float*)d_in[1];
    const int T = in_sizes[0] / (ROUTER_H4 * 4);     // 16384
    (void)n_in; (void)d_ws; (void)ws_size; (void)out_size;

    float* out = (float*)d_out;
    float* out_scores = out;
    float* out_w   = out + (size_t)T * ROUTER_E;
    float* out_idx = out_w + (size_t)T * 2;

    const int rows_per_block = 16 * ROWS_PER_WAVE;   // 64
    const int grid = (T + rows_per_block - 1) / rows_per_block;  // 256 = #CUs
    learned_router_kernel<<<grid, 1024, 0, stream>>>(x, W, out_scores, out_w, out_idx, T);
}